// Round 1
// baseline (5626.690 us; speedup 1.0000x reference)
//
#include <hip/hip_runtime.h>

// SparseGCNConv: out = segment_sum(norm * f[src], dst, N) @ W^T + bias
// Strategy (round 1 baseline):
//   1) g = f @ W^T  (GEMM first -- linear commutes with segment_sum)
//   2) out[n][:] = bias
//   3) per-edge: out[dst] += norm * g[src]  (fp32 HW atomics)
//
// N=100000, E=3200000, D_IN=D_OUT=128. All fp32.

#define NN 100000
#define NE 3200000
#define D  128

// ---------------------------------------------------------------------------
// Kernel 1: g = f @ W^T.  g[n][c] = sum_k f[n][k] * w[c][k]
// Block: 256 threads, 16 nodes per block. 6250 blocks (exact, 100000 = 6250*16).
// W (64 KB) staged in LDS with XOR swizzle: wlds[c*128 + (k ^ (c&31))].
//  - store (lanes vary k, c fixed): banks = (k^cx)%32 -> conflict-free
//  - compute read (lanes vary c, k uniform): banks = (k^(c&31))%32 -> 2-way (free)
// f rows are wave-uniform (jbase via readfirstlane) -> compiler can scalarize
// the f loads (s_load), so the inner loop is 1 ds_read + 8 v_fma per k.
__global__ __launch_bounds__(256) void gemm_kernel(
    const float* __restrict__ f, const float* __restrict__ w,
    float* __restrict__ g) {
  __shared__ float wlds[D * D];  // 65536 B
  const int t = threadIdx.x;

  // stage W transposed+swizzled; global reads coalesced (w[i] linear)
  for (int i = t; i < D * D; i += 256) {
    int c = i >> 7;
    int k = i & 127;
    wlds[(c << 7) + (k ^ (c & 31))] = w[i];
  }
  __syncthreads();

  const int c = t & 127;
  const int cx = c & 31;
  const int cbase = c << 7;
  // jbase is physically wave-uniform (t>>7 constant across a 64-lane wave);
  // readfirstlane makes it an SGPR so the f row pointer is uniform -> s_load.
  const int jbase = __builtin_amdgcn_readfirstlane((t >> 7) << 3);  // 0 or 8
  const long nb = (long)blockIdx.x * 16 + jbase;
  const float* __restrict__ frow = f + nb * D;

  float acc[8] = {0.f, 0.f, 0.f, 0.f, 0.f, 0.f, 0.f, 0.f};
#pragma unroll 4
  for (int k = 0; k < D; ++k) {
    float wv = wlds[cbase + (k ^ cx)];
#pragma unroll
    for (int j = 0; j < 8; ++j) {
      acc[j] += frow[j * D + k] * wv;
    }
  }
#pragma unroll
  for (int j = 0; j < 8; ++j) {
    g[(nb + j) * D + c] = acc[j];  // coalesced (lanes vary c)
  }
}

// ---------------------------------------------------------------------------
// Kernel 2: out[n][c] = bias[c], vectorized float4. 12.8M floats = 3.2M float4.
__global__ __launch_bounds__(256) void init_kernel(
    const float* __restrict__ bias, float4* __restrict__ out) {
  const int i = blockIdx.x * 256 + threadIdx.x;  // 3.2M float4s, 12500 blocks
  const float4* b4 = (const float4*)bias;
  out[i] = b4[i & 31];  // (i*4) % 128 channel base; bias hot in L1
}

// ---------------------------------------------------------------------------
// Kernel 3: per-edge scatter. 32 lanes per edge, float4 (4 channels) per lane.
// Gather of g[src] is coalesced 512B/edge and L3-resident (g = 51 MB < 256 MB).
// 4 fp32 HW atomics per thread -> 409.6M atomics total (the round-1 cost).
__global__ __launch_bounds__(256) void scatter_kernel(
    const float* __restrict__ g, const float* __restrict__ norm,
    const int* __restrict__ src, const int* __restrict__ dst,
    float* __restrict__ out) {
  const long tid = (long)blockIdx.x * 256 + threadIdx.x;
  const int e = (int)(tid >> 5);
  if (e >= NE) return;
  const int ch = (int)(tid & 31) << 2;  // channel base 0..124

  const int s = src[e];
  const int d = dst[e];
  const float nr = norm[e];

  const float4 gv = *(const float4*)(g + (long)s * D + ch);
  float* op = out + (long)d * D + ch;
  unsafeAtomicAdd(op + 0, nr * gv.x);
  unsafeAtomicAdd(op + 1, nr * gv.y);
  unsafeAtomicAdd(op + 2, nr * gv.z);
  unsafeAtomicAdd(op + 3, nr * gv.w);
}

// ---------------------------------------------------------------------------
extern "C" void kernel_launch(void* const* d_in, const int* in_sizes, int n_in,
                              void* d_out, int out_size, void* d_ws,
                              size_t ws_size, hipStream_t stream) {
  const float* features = (const float*)d_in[0];  // [100000,128] f32
  const float* norm     = (const float*)d_in[1];  // [3200000,1] f32
  const int*   src      = (const int*)d_in[2];    // [3200000] i32
  const int*   dst      = (const int*)d_in[3];    // [3200000] i32
  const float* weight   = (const float*)d_in[4];  // [128,128] f32
  const float* bias     = (const float*)d_in[5];  // [128] f32
  float* out = (float*)d_out;                     // [100000,128] f32
  float* g   = (float*)d_ws;                      // scratch: 51.2 MB

  // 1) g = f @ W^T
  hipLaunchKernelGGL(gemm_kernel, dim3(NN / 16), dim3(256), 0, stream,
                     features, weight, g);
  // 2) out = bias (broadcast)
  hipLaunchKernelGGL(init_kernel, dim3((NN * D / 4) / 256), dim3(256), 0,
                     stream, bias, (float4*)out);
  // 3) out[dst] += norm * g[src]
  hipLaunchKernelGGL(scatter_kernel, dim3((long)NE * 32 / 256), dim3(256), 0,
                     stream, g, norm, src, dst, out);
}

// Round 2
// 906.937 us; speedup vs baseline: 6.2041x; 6.2041x over previous
//
#include <hip/hip_runtime.h>

// SparseGCNConv: out = segment_sum(norm * f[src], dst, N) @ W^T + bias
// R2: g = f@W^T, then CSR-by-dst counting sort, then atomic-free pull.
// R1 post-mortem: 409.6M fp32 atomics -> 6.55 GB HBM writes (128x write amp),
// scatter = 5330 us at 1.3% VALU / 17% HBM. CSR pull replaces them with
// 6.4M int atomics on a 400KB L2-resident counter array.

#define NN 100000
#define NE 3200000
#define D  128
#define NBLK 391  // ceil(100000/256)

// ---------------------------------------------------------------------------
// g = f @ W^T  (unchanged from R1; proven correct)
__global__ __launch_bounds__(256) void gemm_kernel(
    const float* __restrict__ f, const float* __restrict__ w,
    float* __restrict__ g) {
  __shared__ float wlds[D * D];  // 64 KB, XOR-swizzled
  const int t = threadIdx.x;
  for (int i = t; i < D * D; i += 256) {
    int c = i >> 7;
    int k = i & 127;
    wlds[(c << 7) + (k ^ (c & 31))] = w[i];
  }
  __syncthreads();

  const int c = t & 127;
  const int cx = c & 31;
  const int cbase = c << 7;
  const int jbase = __builtin_amdgcn_readfirstlane((t >> 7) << 3);  // 0 or 8
  const long nb = (long)blockIdx.x * 16 + jbase;
  const float* __restrict__ frow = f + nb * D;

  float acc[8] = {0.f, 0.f, 0.f, 0.f, 0.f, 0.f, 0.f, 0.f};
#pragma unroll 4
  for (int k = 0; k < D; ++k) {
    float wv = wlds[cbase + (k ^ cx)];
#pragma unroll
    for (int j = 0; j < 8; ++j) acc[j] += frow[j * D + k] * wv;
  }
#pragma unroll
  for (int j = 0; j < 8; ++j) g[(nb + j) * D + c] = acc[j];
}

// ---------------------------------------------------------------------------
// CSR construction: zero counts -> histogram -> scan(3) -> fill
__global__ __launch_bounds__(256) void zero_counts_kernel(int* __restrict__ cnt) {
  int i = blockIdx.x * 256 + threadIdx.x;
  if (i < NN) cnt[i] = 0;
}

__global__ __launch_bounds__(256) void hist_kernel(const int* __restrict__ dst,
                                                   int* __restrict__ cnt) {
  int e = blockIdx.x * 256 + threadIdx.x;
  if (e < NE) atomicAdd(&cnt[dst[e]], 1);
}

// per-256-block exclusive scan; block totals to bsums
__global__ __launch_bounds__(256) void scan_blk_kernel(
    const int* __restrict__ cnt, int* __restrict__ row_ptr,
    int* __restrict__ bsums) {
  __shared__ int s[256];
  const int t = threadIdx.x;
  const int i = blockIdx.x * 256 + t;
  int v = (i < NN) ? cnt[i] : 0;
  s[t] = v;
  __syncthreads();
#pragma unroll
  for (int off = 1; off < 256; off <<= 1) {
    int x = (t >= off) ? s[t - off] : 0;
    __syncthreads();
    s[t] += x;
    __syncthreads();
  }
  if (i < NN) row_ptr[i] = s[t] - v;  // exclusive, per-block
  if (t == 255) bsums[blockIdx.x] = s[255];
}

// single-block exclusive scan of NBLK block sums (NBLK=391 <= 512)
__global__ __launch_bounds__(512) void scan_top_kernel(int* __restrict__ bsums) {
  __shared__ int s[512];
  const int t = threadIdx.x;
  int v = (t < NBLK) ? bsums[t] : 0;
  s[t] = v;
  __syncthreads();
#pragma unroll
  for (int off = 1; off < 512; off <<= 1) {
    int x = (t >= off) ? s[t - off] : 0;
    __syncthreads();
    s[t] += x;
    __syncthreads();
  }
  if (t < NBLK) bsums[t] = s[t] - v;  // exclusive
}

// add block offsets; produce final row_ptr and the running write cursors
__global__ __launch_bounds__(256) void scan_add_kernel(
    int* __restrict__ row_ptr, const int* __restrict__ bsums,
    int* __restrict__ woff) {
  int i = blockIdx.x * 256 + threadIdx.x;
  if (i < NN) {
    int v = row_ptr[i] + bsums[blockIdx.x];
    row_ptr[i] = v;
    woff[i] = v;
  }
  if (i == 0) row_ptr[NN] = NE;
}

// bucket-fill: meta[pos] = {src, norm} sorted by dst
__global__ __launch_bounds__(256) void fill_kernel(
    const int* __restrict__ src, const int* __restrict__ dst,
    const float* __restrict__ norm, int* __restrict__ woff,
    int2* __restrict__ meta) {
  int e = blockIdx.x * 256 + threadIdx.x;
  if (e < NE) {
    int d = dst[e];
    int pos = atomicAdd(&woff[d], 1);
    meta[pos] = make_int2(src[e], __float_as_int(norm[e]));
  }
}

// ---------------------------------------------------------------------------
// Pull: one wave per node, lane holds channels {2l, 2l+1}. No atomics.
// n forced into SGPR -> row_ptr/meta become scalar loads; g gather is a
// 512B coalesced row read, L3-resident (g = 51.2 MB).
__global__ __launch_bounds__(256) void pull_kernel(
    const float* __restrict__ g, const int* __restrict__ row_ptr,
    const int2* __restrict__ meta, const float* __restrict__ bias,
    float* __restrict__ out) {
  int n0 = blockIdx.x * 4 + (threadIdx.x >> 6);
  const int n = __builtin_amdgcn_readfirstlane(n0);  // wave-uniform
  if (n >= NN) return;
  const int lane = threadIdx.x & 63;
  const int ch = lane << 1;
  const int beg = row_ptr[n];
  const int end = row_ptr[n + 1];
  float2 acc = make_float2(0.f, 0.f);
  for (int e = beg; e < end; ++e) {
    int2 m = meta[e];
    float nr = __int_as_float(m.y);
    float2 gv = *(const float2*)(g + (long)m.x * D + ch);
    acc.x += nr * gv.x;
    acc.y += nr * gv.y;
  }
  const float2 b2 = *(const float2*)(bias + ch);
  float2 r = make_float2(acc.x + b2.x, acc.y + b2.y);
  *(float2*)(out + (long)n * D + ch) = r;
}

// ---------------------------------------------------------------------------
// R1 fallback (used only if ws_size too small for the CSR path)
__global__ __launch_bounds__(256) void init_kernel(
    const float* __restrict__ bias, float4* __restrict__ out) {
  const int i = blockIdx.x * 256 + threadIdx.x;
  const float4* b4 = (const float4*)bias;
  out[i] = b4[i & 31];
}

__global__ __launch_bounds__(256) void scatter_kernel(
    const float* __restrict__ g, const float* __restrict__ norm,
    const int* __restrict__ src, const int* __restrict__ dst,
    float* __restrict__ out) {
  const long tid = (long)blockIdx.x * 256 + threadIdx.x;
  const int e = (int)(tid >> 5);
  if (e >= NE) return;
  const int ch = (int)(tid & 31) << 2;
  const int s = src[e];
  const int d = dst[e];
  const float nr = norm[e];
  const float4 gv = *(const float4*)(g + (long)s * D + ch);
  float* op = out + (long)d * D + ch;
  unsafeAtomicAdd(op + 0, nr * gv.x);
  unsafeAtomicAdd(op + 1, nr * gv.y);
  unsafeAtomicAdd(op + 2, nr * gv.z);
  unsafeAtomicAdd(op + 3, nr * gv.w);
}

// ---------------------------------------------------------------------------
extern "C" void kernel_launch(void* const* d_in, const int* in_sizes, int n_in,
                              void* d_out, int out_size, void* d_ws,
                              size_t ws_size, hipStream_t stream) {
  const float* features = (const float*)d_in[0];
  const float* norm     = (const float*)d_in[1];
  const int*   src      = (const int*)d_in[2];
  const int*   dst      = (const int*)d_in[3];
  const float* weight   = (const float*)d_in[4];
  const float* bias     = (const float*)d_in[5];
  float* out = (float*)d_out;

  // ws layout
  char* ws = (char*)d_ws;
  float* g      = (float*)ws;                         // 51,200,000 B
  int* row_ptr  = (int*)(ws + 51200000);              //    400,128 B (100001 ints)
  int* woff     = (int*)(ws + 51600128);              //    400,000 B
  int* bsums    = (int*)(ws + 52000128);              //      2,048 B
  int2* meta    = (int2*)(ws + 52002176);             // 25,600,000 B
  const size_t need = 77602176;

  hipLaunchKernelGGL(gemm_kernel, dim3(NN / 16), dim3(256), 0, stream,
                     features, weight, g);

  if (ws_size >= need) {
    // CSR-by-dst counting sort
    hipLaunchKernelGGL(zero_counts_kernel, dim3(NBLK), dim3(256), 0, stream, woff);
    hipLaunchKernelGGL(hist_kernel, dim3(NE / 256), dim3(256), 0, stream, dst, woff);
    hipLaunchKernelGGL(scan_blk_kernel, dim3(NBLK), dim3(256), 0, stream,
                       woff, row_ptr, bsums);
    hipLaunchKernelGGL(scan_top_kernel, dim3(1), dim3(512), 0, stream, bsums);
    hipLaunchKernelGGL(scan_add_kernel, dim3(NBLK), dim3(256), 0, stream,
                       row_ptr, bsums, woff);
    hipLaunchKernelGGL(fill_kernel, dim3(NE / 256), dim3(256), 0, stream,
                       src, dst, norm, woff, meta);
    // atomic-free pull (writes bias too)
    hipLaunchKernelGGL(pull_kernel, dim3(NN / 4), dim3(256), 0, stream,
                       g, row_ptr, meta, bias, out);
  } else {
    // R1 fallback
    hipLaunchKernelGGL(init_kernel, dim3((NN * D / 4) / 256), dim3(256), 0,
                       stream, bias, (float4*)out);
    hipLaunchKernelGGL(scatter_kernel, dim3((long)NE * 32 / 256), dim3(256), 0,
                       stream, g, norm, src, dst, out);
  }
}